// Round 16
// baseline (659.649 us; speedup 1.0000x reference)
//
#include <hip/hip_runtime.h>
#include <hip/hip_bf16.h>

#define N_NODES 65536
#define N_EDGES 1048576
#define IN_DIM 96
#define HID 128
#define OUTD 256
#define N_ACT 20

typedef unsigned short u16;
typedef unsigned char u8;
typedef unsigned int u32;
typedef __attribute__((ext_vector_type(8))) short bf16x8;
typedef __attribute__((ext_vector_type(4))) float f32x4;

// intermediates bf16 (xr/hres) and fp8-e4m3 (xl, gather-path) ; all math fp32
__device__ __forceinline__ float bf2f(u16 v) { return __uint_as_float(((u32)v) << 16); }
__device__ __forceinline__ u16 f2bf(float f) {
    u32 x = __float_as_uint(f);
    return (u16)((x + 0x7fffu + ((x >> 16) & 1u)) >> 16);
}

// ---- fp8 e4m3fn (OCP) SW codecs ----
__device__ __forceinline__ float f8dec(u32 t) {
    return __uint_as_float(((t & 0x7fu) | ((t & 0x80u) << 4)) << 20) * 0x1p120f;
}
__device__ __forceinline__ u8 ftofp8(float f) {
    f = fminf(fmaxf(f, -448.f), 448.f);
    u32 b = __float_as_uint(f);
    u32 s = (b >> 24) & 0x80u;
    u32 ax = b & 0x7fffffffu;
    if (__uint_as_float(ax) < 0.015625f) {           // |f| < 2^-6 -> denormal m/512
        u32 mi = (u32)rintf(__uint_as_float(ax) * 512.f);
        return (u8)(s | mi);
    }
    u32 q = ax >> 20;
    u32 rem = ax & 0xFFFFFu;
    q += (rem > 0x80000u || (rem == 0x80000u && (q & 1u))) ? 1u : 0u;
    return (u8)(s | (q - 960u));                     // 960 = 120<<3 exponent rebias
}

// ---- DPP adds on the VALU pipe (ctrl must be a constant -> template) ----
template <int CTRL>
__device__ __forceinline__ float dppadd(float p) {
    return p + __uint_as_float((u32)__builtin_amdgcn_update_dpp(
        0, (int)__float_as_uint(p), CTRL, 0xF, 0xF, true));
}
// full-wave sum, result broadcast (readlane 63)
__device__ __forceinline__ float wave_sum_bcast(float p) {
    p = dppadd<0x111>(p);   // row_shr:1
    p = dppadd<0x112>(p);   // row_shr:2
    p = dppadd<0x114>(p);   // row_shr:4
    p = dppadd<0x118>(p);   // row_shr:8
    p = dppadd<0x142>(p);   // row_bcast15
    p = dppadd<0x143>(p);   // row_bcast31
    return __uint_as_float((u32)__builtin_amdgcn_readlane((int)__float_as_uint(p), 63));
}

// ---------------- prep: zero deg/cursor + bf16 n-major weights + transpose Wq ----------------
__global__ __launch_bounds__(256) void k_prep(
    int* __restrict__ deg,
    const float* __restrict__ Wl, const float* __restrict__ Wr, const float* __restrict__ Wres,
    u16* __restrict__ wt,
    const float* __restrict__ W0, u16* __restrict__ wt0,
    const float* __restrict__ W1, u16* __restrict__ wt1,
    const float* __restrict__ Wq, float* __restrict__ wqT)
{
    int b = blockIdx.x, t = threadIdx.x;
    if (b < 512) {
        deg[b * 256 + t] = 0;                 // deg + cursor (contiguous)
    } else if (b < 896) {
        int idx = (b - 512) * 256 + t;        // 0..98303  gat weights [768][128]
        int nn = idx >> 7, k = idx & 127;
        float v;
        if (nn < 256) v = Wl[k * OUTD + nn];
        else if (nn < 512) v = Wr[k * OUTD + (nn - 256)];
        else v = Wres[k * OUTD + (nn - 512)];
        wt[idx] = f2bf(v);
    } else if (b < 944) {
        int idx = (b - 896) * 256 + t;        // 0..12287  W0^T [128][96]
        int nn = idx / 96, k = idx - nn * 96;
        wt0[idx] = f2bf(W0[k * HID + nn]);
    } else if (b < 1008) {
        int idx = (b - 944) * 256 + t;        // 0..16383  W1^T [128][128]
        int nn = idx >> 7, k = idx & 127;
        wt1[idx] = f2bf(W1[k * HID + nn]);
    } else {
        int idx = (b - 1008) * 256 + t;       // 0..5119   Wq^T [20][256]
        int q = idx >> 8, d = idx & 255;
        wqT[q * OUTD + d] = Wq[d * N_ACT + q];
    }
}

// ---------------- exclusive scan of degrees -> CSR offsets (int4-vectorized) ----------------
__global__ __launch_bounds__(1024) void k_scan(const int* __restrict__ deg, int* __restrict__ off) {
    __shared__ int part[1024];
    int t = threadIdx.x;
    int base = t * 64;
    const int4* d4 = (const int4*)(deg + base);
    int s = 0;
#pragma unroll
    for (int i = 0; i < 16; i++) { int4 v = d4[i]; s += v.x + v.y + v.z + v.w; }
    part[t] = s;
    __syncthreads();
    for (int o = 1; o < 1024; o <<= 1) {
        int v = (t >= o) ? part[t - o] : 0;
        __syncthreads();
        part[t] += v;
        __syncthreads();
    }
    int run = (t == 0) ? 0 : part[t - 1];
    int4* o4 = (int4*)(off + base);
#pragma unroll
    for (int i = 0; i < 16; i++) {
        int4 v = d4[i];
        int4 w;
        w.x = run;
        w.y = run + v.x;
        w.z = w.y + v.y;
        w.w = w.z + v.z;
        run = w.w + v.w;
        o4[i] = w;
    }
    if (t == 1023) off[N_NODES] = run;
}

// ---------------- scatter edge records (src + 3 attrs) into CSR order ----------------
__global__ __launch_bounds__(256) void k_scatter(
    const int* __restrict__ ei, const float* __restrict__ ea,
    const int* __restrict__ off, int* __restrict__ cursor,
    int4* __restrict__ erec)
{
    int e = blockIdx.x * 256 + threadIdx.x;
    int src = ei[e];
    int dst = ei[N_EDGES + e];
    float a0 = ea[e * 3 + 0];
    float a1 = ea[e * 3 + 1];
    float a2 = ea[e * 3 + 2];
    int pos = off[dst] + atomicAdd(cursor + dst, 1);
    erec[pos] = make_int4(src, __float_as_int(a0), __float_as_int(a1), __float_as_int(a2));
}

// ---------------- fused node pipeline (MFMA, TRANSPOSED): MLP(2x LN) -> xl8/xr/hres ----------------
// Operand swap vs R12-R15: A = weights (outcols = M), B = node activations (nodes = N).
// D: col=lane&15 = node, row = outcol -> each lane holds 4 CONSECUTIVE outcols of one
// node -> epilogue stores are contiguous ushort4/u32 (was 2B col-stride-16 scatter:
// ~25M partial-line L2 touches). LN reduce: per-lane sum + shfl_xor(16/32) across quads.
// blocks [0,1024): 4 waves x 16 nodes; blocks [1024,5120): degree count (overlapped).
__global__ __launch_bounds__(256, 4) void k_fused(
    const float* __restrict__ in,
    const u16* __restrict__ wt0, const u16* __restrict__ wt1, const u16* __restrict__ wt,
    const float* __restrict__ b0, const float* __restrict__ g0, const float* __restrict__ be0,
    const float* __restrict__ b1, const float* __restrict__ g1, const float* __restrict__ be1,
    const float* __restrict__ bl, const float* __restrict__ br, const float* __restrict__ gbias,
    const int* __restrict__ ei, int* __restrict__ deg,
    u8* __restrict__ xl8, u16* __restrict__ xr, u16* __restrict__ hres)
{
    if (blockIdx.x >= 1024) {
        int e = (blockIdx.x - 1024) * 256 + threadIdx.x;
        atomicAdd(deg + ei[N_EDGES + e], 1);
        return;
    }
    int wid = threadIdx.x >> 6, lane = threadIdx.x & 63;
    int l15 = lane & 15, quad = lane >> 4;
    int m0 = (blockIdx.x * 4 + wid) * 16;

    __shared__ u16 xbuf[4][16][136];   // per-wave x-strip (bf16), row = node

    f32x4 acc[8];

    // ===== layer 0: D[outcol][node], A=wt0 (outcol-major), B=x_in (node rows) =====
#pragma unroll
    for (int t = 0; t < 8; t++) acc[t] = {0.f, 0.f, 0.f, 0.f};
#pragma unroll
    for (int kk = 0; kk < 3; kk++) {
        const float* ap = in + (long)(m0 + l15) * IN_DIM + kk * 32 + quad * 8;
        float4 fa = *(const float4*)(ap);
        float4 fb = *(const float4*)(ap + 4);
        bf16x8 xf;
        xf[0] = (short)f2bf(fa.x); xf[1] = (short)f2bf(fa.y);
        xf[2] = (short)f2bf(fa.z); xf[3] = (short)f2bf(fa.w);
        xf[4] = (short)f2bf(fb.x); xf[5] = (short)f2bf(fb.y);
        xf[6] = (short)f2bf(fb.z); xf[7] = (short)f2bf(fb.w);
#pragma unroll
        for (int t = 0; t < 8; t++) {
            bf16x8 wf = *(const bf16x8*)(wt0 + (t * 16 + l15) * IN_DIM + kk * 32 + quad * 8);
            acc[t] = __builtin_amdgcn_mfma_f32_16x16x32_bf16(wf, xf, acc[t], 0, 0, 0);
        }
    }
    {
        float s_ = 0.f, q_ = 0.f;
#pragma unroll
        for (int t = 0; t < 8; t++) {
            float4 bv = *(const float4*)(b0 + t * 16 + quad * 4);
#pragma unroll
            for (int g = 0; g < 4; g++) {
                float x = fmaxf(acc[t][g] + bv[g], 0.f);
                acc[t][g] = x;
                s_ += x;
                q_ = fmaf(x, x, q_);
            }
        }
        s_ += __shfl_xor(s_, 16, 64); s_ += __shfl_xor(s_, 32, 64);
        q_ += __shfl_xor(q_, 16, 64); q_ += __shfl_xor(q_, 32, 64);
        float mu = s_ * (1.f / HID);
        float var = q_ * (1.f / HID) - mu * mu;
        float rs = rsqrtf(fmaxf(var, 0.f) + 1e-5f);
#pragma unroll
        for (int t = 0; t < 8; t++) {
            float4 gv = *(const float4*)(g0 + t * 16 + quad * 4);
            float4 ev = *(const float4*)(be0 + t * 16 + quad * 4);
            ushort4 y;
            y.x = f2bf((acc[t][0] - mu) * rs * gv.x + ev.x);
            y.y = f2bf((acc[t][1] - mu) * rs * gv.y + ev.y);
            y.z = f2bf((acc[t][2] - mu) * rs * gv.z + ev.z);
            y.w = f2bf((acc[t][3] - mu) * rs * gv.w + ev.w);
            *(ushort4*)(&xbuf[wid][l15][t * 16 + quad * 4]) = y;
        }
    }

    // ===== layer 1: same transposed scheme, A=wt1, B=xbuf =====
#pragma unroll
    for (int t = 0; t < 8; t++) acc[t] = {0.f, 0.f, 0.f, 0.f};
#pragma unroll
    for (int kk = 0; kk < 4; kk++) {
        bf16x8 xf = *(const bf16x8*)(&xbuf[wid][l15][kk * 32 + quad * 8]);
#pragma unroll
        for (int t = 0; t < 8; t++) {
            bf16x8 wf = *(const bf16x8*)(wt1 + (t * 16 + l15) * HID + kk * 32 + quad * 8);
            acc[t] = __builtin_amdgcn_mfma_f32_16x16x32_bf16(wf, xf, acc[t], 0, 0, 0);
        }
    }
    {
        float s_ = 0.f, q_ = 0.f;
#pragma unroll
        for (int t = 0; t < 8; t++) {
            float4 bv = *(const float4*)(b1 + t * 16 + quad * 4);
#pragma unroll
            for (int g = 0; g < 4; g++) {
                float x = fmaxf(acc[t][g] + bv[g], 0.f);
                acc[t][g] = x;
                s_ += x;
                q_ = fmaf(x, x, q_);
            }
        }
        s_ += __shfl_xor(s_, 16, 64); s_ += __shfl_xor(s_, 32, 64);
        q_ += __shfl_xor(q_, 16, 64); q_ += __shfl_xor(q_, 32, 64);
        float mu = s_ * (1.f / HID);
        float var = q_ * (1.f / HID) - mu * mu;
        float rs = rsqrtf(fmaxf(var, 0.f) + 1e-5f);
#pragma unroll
        for (int t = 0; t < 8; t++) {
            float4 gv = *(const float4*)(g1 + t * 16 + quad * 4);
            float4 ev = *(const float4*)(be1 + t * 16 + quad * 4);
            ushort4 y;
            y.x = f2bf((acc[t][0] - mu) * rs * gv.x + ev.x);
            y.y = f2bf((acc[t][1] - mu) * rs * gv.y + ev.y);
            y.z = f2bf((acc[t][2] - mu) * rs * gv.z + ev.z);
            y.w = f2bf((acc[t][3] - mu) * rs * gv.w + ev.w);
            *(ushort4*)(&xbuf[wid][l15][t * 16 + quad * 4]) = y;
        }
    }

    // ===== projections: A=wt (outcol-major), B=xbuf -> contiguous stores =====
    for (int nT = 0; nT < 3; nT++) {
        f32x4 pacc[16];
#pragma unroll
        for (int t = 0; t < 16; t++) pacc[t] = {0.f, 0.f, 0.f, 0.f};
#pragma unroll
        for (int kk = 0; kk < 4; kk++) {
            bf16x8 xf = *(const bf16x8*)(&xbuf[wid][l15][kk * 32 + quad * 8]);
#pragma unroll
            for (int t = 0; t < 16; t++) {
                bf16x8 wf = *(const bf16x8*)(wt + (long)(nT * 256 + t * 16 + l15) * HID + kk * 32 + quad * 8);
                pacc[t] = __builtin_amdgcn_mfma_f32_16x16x32_bf16(wf, xf, pacc[t], 0, 0, 0);
            }
        }
        long node = m0 + l15;
        if (nT == 0) {
#pragma unroll
            for (int t = 0; t < 16; t++) {
                float4 bv = *(const float4*)(bl + t * 16 + quad * 4);
                u32 pk = (u32)ftofp8(pacc[t][0] + bv.x)
                       | ((u32)ftofp8(pacc[t][1] + bv.y) << 8)
                       | ((u32)ftofp8(pacc[t][2] + bv.z) << 16)
                       | ((u32)ftofp8(pacc[t][3] + bv.w) << 24);
                *(u32*)(xl8 + node * OUTD + t * 16 + quad * 4) = pk;
            }
        } else {
            const float* bias = (nT == 1) ? br : gbias;
            u16* dst = (nT == 1) ? xr : hres;
#pragma unroll
            for (int t = 0; t < 16; t++) {
                float4 bv = *(const float4*)(bias + t * 16 + quad * 4);
                ushort4 y;
                y.x = f2bf(pacc[t][0] + bv.x);
                y.y = f2bf(pacc[t][1] + bv.y);
                y.z = f2bf(pacc[t][2] + bv.z);
                y.w = f2bf(pacc[t][3] + bv.w);
                *(ushort4*)(dst + node * OUTD + t * 16 + quad * 4) = y;
            }
        }
    }
}

// ---------------- fused aggregation (R15, measured 312 µs): plain-exp softmax, ----------------
// 2 edges/iter, pipelined, DPP wave-sum, fp8 xl gather (256B rows).
__global__ __launch_bounds__(256, 6) void k_agg_fused(
    const int* __restrict__ off, const int4* __restrict__ erec,
    const u8* __restrict__ xl8, const u16* __restrict__ xr, const u16* __restrict__ hres,
    const float* __restrict__ We, const float* __restrict__ att,
    const float* __restrict__ g2, const float* __restrict__ be2,
    const float* __restrict__ wqT, const float* __restrict__ bq,
    float* __restrict__ out)
{
    int wid = threadIdx.x >> 6, lane = threadIdx.x & 63;
    int n = blockIdx.x * 4 + wid;
    int j0 = lane * 4;
    __shared__ float lds[4][OUTD + 4];

    float4 w0 = *(const float4*)(We + j0);
    float4 w1 = *(const float4*)(We + OUTD + j0);
    float4 w2 = *(const float4*)(We + 2 * OUTD + j0);
    float4 av = *(const float4*)(att + j0);

    ushort4 xrv = *(const ushort4*)(xr + (long)n * OUTD + j0);
    float xr0 = bf2f(xrv.x), xr1 = bf2f(xrv.y), xr2 = bf2f(xrv.z), xr3 = bf2f(xrv.w);

    int beg = off[n], end = off[n + 1];

    float s = 0.f;
    float a0 = 0.f, a1 = 0.f, a2 = 0.f, a3 = 0.f;

    if (beg < end) {
        int4 r0 = erec[beg];
        int4 r1 = erec[(beg + 1 < end) ? beg + 1 : beg];
        u32 v0 = *(const u32*)(xl8 + (long)r0.x * OUTD + j0);
        u32 v1 = *(const u32*)(xl8 + (long)r1.x * OUTD + j0);

        for (int i = beg; i < end; i += 2) {
            int ip2 = (i + 2 < end) ? i + 2 : end - 1;
            int ip3 = (i + 3 < end) ? i + 3 : end - 1;
            int4 nr0 = erec[ip2];
            int4 nr1 = erec[ip3];
            u32 nv0 = *(const u32*)(xl8 + (long)nr0.x * OUTD + j0);
            u32 nv1 = *(const u32*)(xl8 + (long)nr1.x * OUTD + j0);

            float x00 = f8dec(v0 & 255u), x01 = f8dec((v0 >> 8) & 255u);
            float x02 = f8dec((v0 >> 16) & 255u), x03 = f8dec(v0 >> 24);
            float x10 = f8dec(v1 & 255u), x11 = f8dec((v1 >> 8) & 255u);
            float x12 = f8dec((v1 >> 16) & 255u), x13 = f8dec(v1 >> 24);

            float p0, p1;
            {
                float ea0 = __int_as_float(r0.y), ea1 = __int_as_float(r0.z), ea2 = __int_as_float(r0.w);
                float t0 = x00 + xr0 + ea0 * w0.x + ea1 * w1.x + ea2 * w2.x;
                float t1 = x01 + xr1 + ea0 * w0.y + ea1 * w1.y + ea2 * w2.y;
                float t2 = x02 + xr2 + ea0 * w0.z + ea1 * w1.z + ea2 * w2.z;
                float t3 = x03 + xr3 + ea0 * w0.w + ea1 * w1.w + ea2 * w2.w;
                p0 = fmaxf(t0, 0.2f * t0) * av.x;
                p0 = fmaf(fmaxf(t1, 0.2f * t1), av.y, p0);
                p0 = fmaf(fmaxf(t2, 0.2f * t2), av.z, p0);
                p0 = fmaf(fmaxf(t3, 0.2f * t3), av.w, p0);
            }
            {
                float ea0 = __int_as_float(r1.y), ea1 = __int_as_float(r1.z), ea2 = __int_as_float(r1.w);
                float t0 = x10 + xr0 + ea0 * w0.x + ea1 * w1.x + ea2 * w2.x;
                float t1 = x11 + xr1 + ea0 * w0.y + ea1 * w1.y + ea2 * w2.y;
                float t2 = x12 + xr2 + ea0 * w0.z + ea1 * w1.z + ea2 * w2.z;
                float t3 = x13 + xr3 + ea0 * w0.w + ea1 * w1.w + ea2 * w2.w;
                p1 = fmaxf(t0, 0.2f * t0) * av.x;
                p1 = fmaf(fmaxf(t1, 0.2f * t1), av.y, p1);
                p1 = fmaf(fmaxf(t2, 0.2f * t2), av.z, p1);
                p1 = fmaf(fmaxf(t3, 0.2f * t3), av.w, p1);
            }

            p0 = wave_sum_bcast(p0);
            p1 = wave_sum_bcast(p1);
            if (i + 1 >= end) p1 = -1.0e30f;   // exp -> 0

            float e0 = __expf(p0);
            float e1 = __expf(p1);
            s += e0 + e1;
            a0 = fmaf(e0, x00, fmaf(e1, x10, a0));
            a1 = fmaf(e0, x01, fmaf(e1, x11, a1));
            a2 = fmaf(e0, x02, fmaf(e1, x12, a2));
            a3 = fmaf(e0, x03, fmaf(e1, x13, a3));

            r0 = nr0; r1 = nr1; v0 = nv0; v1 = nv1;
        }
    }

    float inv = (end > beg) ? 1.f / s : 0.f;

    ushort4 hv = *(const ushort4*)(hres + (long)n * OUTD + j0);
    float h0 = fmaxf(fmaf(a0, inv, bf2f(hv.x)), 0.f);
    float h1 = fmaxf(fmaf(a1, inv, bf2f(hv.y)), 0.f);
    float h2 = fmaxf(fmaf(a2, inv, bf2f(hv.z)), 0.f);
    float h3 = fmaxf(fmaf(a3, inv, bf2f(hv.w)), 0.f);

    float sum = h0 + h1 + h2 + h3;
    float sq = h0 * h0 + h1 * h1 + h2 * h2 + h3 * h3;
    sum = wave_sum_bcast(sum);
    sq = wave_sum_bcast(sq);
    float mu = sum * (1.f / OUTD);
    float var = sq * (1.f / OUTD) - mu * mu;
    float rs = rsqrtf(fmaxf(var, 0.f) + 1e-5f);

    float4 gv = *(const float4*)(g2 + j0);
    float4 bv = *(const float4*)(be2 + j0);
    float4 y;
    y.x = (h0 - mu) * rs * gv.x + bv.x;
    y.y = (h1 - mu) * rs * gv.y + bv.y;
    y.z = (h2 - mu) * rs * gv.z + bv.z;
    y.w = (h3 - mu) * rs * gv.w + bv.w;
    *(float4*)(&lds[wid][j0]) = y;
    __syncthreads();

    if (lane < N_ACT) {
        const float* wq = wqT + lane * OUTD;
        float qv = bq[lane];
#pragma unroll 4
        for (int j = 0; j < OUTD; j += 4) {
            float4 lv = *(const float4*)(&lds[wid][j]);
            float4 wv = *(const float4*)(wq + j);
            qv = fmaf(lv.x, wv.x, qv);
            qv = fmaf(lv.y, wv.y, qv);
            qv = fmaf(lv.z, wv.z, qv);
            qv = fmaf(lv.w, wv.w, qv);
        }
        out[(long)n * N_ACT + lane] = qv;
    }
}

extern "C" void kernel_launch(void* const* d_in, const int* in_sizes, int n_in,
                              void* d_out, int out_size, void* d_ws, size_t ws_size,
                              hipStream_t stream) {
    (void)in_sizes; (void)n_in; (void)out_size; (void)ws_size;
    const float* inp  = (const float*)d_in[0];
    const int*   ei   = (const int*)d_in[1];
    const float* ea   = (const float*)d_in[2];
    const float* W0   = (const float*)d_in[3];
    const float* b0   = (const float*)d_in[4];
    const float* g0   = (const float*)d_in[5];
    const float* be0  = (const float*)d_in[6];
    const float* W1   = (const float*)d_in[7];
    const float* b1   = (const float*)d_in[8];
    const float* g1   = (const float*)d_in[9];
    const float* be1  = (const float*)d_in[10];
    const float* Wl   = (const float*)d_in[11];
    const float* bl   = (const float*)d_in[12];
    const float* Wr   = (const float*)d_in[13];
    const float* br   = (const float*)d_in[14];
    const float* We   = (const float*)d_in[15];
    const float* att  = (const float*)d_in[16];
    const float* Wres = (const float*)d_in[17];
    const float* gbias= (const float*)d_in[18];
    const float* g2   = (const float*)d_in[19];
    const float* be2  = (const float*)d_in[20];
    const float* Wq   = (const float*)d_in[21];
    const float* bq   = (const float*)d_in[22];
    float* out = (float*)d_out;

    char* ws = (char*)d_ws;
    size_t o = 0;
    auto alloc = [&](size_t bytes) -> void* {
        void* p = ws + o;
        o += (bytes + 255) & ~(size_t)255;
        return p;
    };
    u8*    xl8    = (u8*)   alloc((size_t)N_NODES * OUTD);        // 16 MiB (fp8 e4m3)
    u16*   xr     = (u16*)  alloc((size_t)N_NODES * OUTD * 2);    // 32 MiB
    u16*   hres   = (u16*)  alloc((size_t)N_NODES * OUTD * 2);    // 32 MiB
    int*   deg    = (int*)  alloc((size_t)N_NODES * 4);           // 256 KiB
    int*   cursor = (int*)  alloc((size_t)N_NODES * 4);           // 256 KiB (contiguous with deg)
    int*   off    = (int*)  alloc((size_t)(N_NODES + 1) * 4);
    int4*  erec   = (int4*) alloc((size_t)N_EDGES * 16);          // 16 MiB
    u16*   wt     = (u16*)  alloc((size_t)768 * HID * 2);         // 192 KiB  gat [768][128]
    u16*   wt0    = (u16*)  alloc((size_t)HID * IN_DIM * 2);      // 24 KiB   W0^T [128][96]
    u16*   wt1    = (u16*)  alloc((size_t)HID * HID * 2);         // 32 KiB   W1^T [128][128]
    float* wqT    = (float*)alloc((size_t)N_ACT * OUTD * 4);      // 20 KiB

    k_prep<<<1028, 256, 0, stream>>>(deg, Wl, Wr, Wres, wt, W0, wt0, W1, wt1, Wq, wqT);
    k_fused<<<1024 + N_EDGES / 256, 256, 0, stream>>>(inp, wt0, wt1, wt,
        b0, g0, be0, b1, g1, be1, bl, br, gbias, ei, deg, xl8, xr, hres);
    k_scan<<<1, 1024, 0, stream>>>(deg, off);
    k_scatter<<<N_EDGES / 256, 256, 0, stream>>>(ei, ea, off, cursor, erec);
    k_agg_fused<<<N_NODES / 4, 256, 0, stream>>>(off, erec, xl8, xr, hres, We, att, g2, be2, wqT, bq, out);
}

// Round 17
// 623.372 us; speedup vs baseline: 1.0582x; 1.0582x over previous
//
#include <hip/hip_runtime.h>
#include <hip/hip_bf16.h>

#define N_NODES 65536
#define N_EDGES 1048576
#define IN_DIM 96
#define HID 128
#define OUTD 256
#define N_ACT 20

typedef unsigned short u16;
typedef unsigned char u8;
typedef unsigned int u32;
typedef __attribute__((ext_vector_type(8))) short bf16x8;
typedef __attribute__((ext_vector_type(4))) float f32x4;

// intermediates bf16 (xr/hres) and fp8-e4m3 (xl, gather-path) ; all math fp32
__device__ __forceinline__ float bf2f(u16 v) { return __uint_as_float(((u32)v) << 16); }
__device__ __forceinline__ u16 f2bf(float f) {
    u32 x = __float_as_uint(f);
    return (u16)((x + 0x7fffu + ((x >> 16) & 1u)) >> 16);
}

// ---- fp8 e4m3fn (OCP) SW codecs ----
__device__ __forceinline__ float f8dec(u32 t) {
    return __uint_as_float(((t & 0x7fu) | ((t & 0x80u) << 4)) << 20) * 0x1p120f;
}
__device__ __forceinline__ u8 ftofp8(float f) {
    f = fminf(fmaxf(f, -448.f), 448.f);
    u32 b = __float_as_uint(f);
    u32 s = (b >> 24) & 0x80u;
    u32 ax = b & 0x7fffffffu;
    if (__uint_as_float(ax) < 0.015625f) {           // |f| < 2^-6 -> denormal m/512
        u32 mi = (u32)rintf(__uint_as_float(ax) * 512.f);
        return (u8)(s | mi);
    }
    u32 q = ax >> 20;
    u32 rem = ax & 0xFFFFFu;
    q += (rem > 0x80000u || (rem == 0x80000u && (q & 1u))) ? 1u : 0u;
    return (u8)(s | (q - 960u));                     // 960 = 120<<3 exponent rebias
}

// ---- DPP adds on the VALU pipe (ctrl must be a constant -> template) ----
template <int CTRL>
__device__ __forceinline__ float dppadd(float p) {
    return p + __uint_as_float((u32)__builtin_amdgcn_update_dpp(
        0, (int)__float_as_uint(p), CTRL, 0xF, 0xF, true));
}
// full-wave sum, result broadcast (readlane 63)
__device__ __forceinline__ float wave_sum_bcast(float p) {
    p = dppadd<0x111>(p);   // row_shr:1
    p = dppadd<0x112>(p);   // row_shr:2
    p = dppadd<0x114>(p);   // row_shr:4
    p = dppadd<0x118>(p);   // row_shr:8
    p = dppadd<0x142>(p);   // row_bcast15
    p = dppadd<0x143>(p);   // row_bcast31
    return __uint_as_float((u32)__builtin_amdgcn_readlane((int)__float_as_uint(p), 63));
}
// 16-lane (hw-row) sum, broadcast to all 16 lanes of the row.
__device__ __forceinline__ float red16(float p) {
    p = dppadd<0xB1>(p);
    p = dppadd<0x4E>(p);
    p = dppadd<0x141>(p);
    p = dppadd<0x140>(p);
    return p;
}

// ---------------- prep: zero deg + bf16 n-major weights + transpose Wq ----------------
__global__ __launch_bounds__(256) void k_prep(
    int* __restrict__ deg,
    const float* __restrict__ Wl, const float* __restrict__ Wr, const float* __restrict__ Wres,
    u16* __restrict__ wt,
    const float* __restrict__ W0, u16* __restrict__ wt0,
    const float* __restrict__ W1, u16* __restrict__ wt1,
    const float* __restrict__ Wq, float* __restrict__ wqT)
{
    int b = blockIdx.x, t = threadIdx.x;
    if (b < 256) {
        deg[b * 256 + t] = 0;
    } else if (b < 640) {
        int idx = (b - 256) * 256 + t;        // 0..98303  gat weights [768][128]
        int nn = idx >> 7, k = idx & 127;
        float v;
        if (nn < 256) v = Wl[k * OUTD + nn];
        else if (nn < 512) v = Wr[k * OUTD + (nn - 256)];
        else v = Wres[k * OUTD + (nn - 512)];
        wt[idx] = f2bf(v);
    } else if (b < 688) {
        int idx = (b - 640) * 256 + t;        // 0..12287  W0^T [128][96]
        int nn = idx / 96, k = idx - nn * 96;
        wt0[idx] = f2bf(W0[k * HID + nn]);
    } else if (b < 752) {
        int idx = (b - 688) * 256 + t;        // 0..16383  W1^T [128][128]
        int nn = idx >> 7, k = idx & 127;
        wt1[idx] = f2bf(W1[k * HID + nn]);
    } else {
        int idx = (b - 752) * 256 + t;        // 0..5119   Wq^T [20][256]
        int q = idx >> 8, d = idx & 255;
        wqT[q * OUTD + d] = Wq[d * N_ACT + q];
    }
}

// ---------------- exclusive scan of degrees -> CSR offsets (int4-vectorized) ----------------
__global__ __launch_bounds__(1024) void k_scan(const int* __restrict__ deg, int* __restrict__ off) {
    __shared__ int part[1024];
    int t = threadIdx.x;
    int base = t * 64;
    const int4* d4 = (const int4*)(deg + base);
    int s = 0;
#pragma unroll
    for (int i = 0; i < 16; i++) { int4 v = d4[i]; s += v.x + v.y + v.z + v.w; }
    part[t] = s;
    __syncthreads();
    for (int o = 1; o < 1024; o <<= 1) {
        int v = (t >= o) ? part[t - o] : 0;
        __syncthreads();
        part[t] += v;
        __syncthreads();
    }
    int run = (t == 0) ? 0 : part[t - 1];
    int4* o4 = (int4*)(off + base);
#pragma unroll
    for (int i = 0; i < 16; i++) {
        int4 v = d4[i];
        int4 w;
        w.x = run;
        w.y = run + v.x;
        w.z = w.y + v.y;
        w.w = w.z + v.z;
        run = w.w + v.w;
        o4[i] = w;
    }
    if (t == 1023) off[N_NODES] = run;
}

// ---------------- scatter edge records into CSR order (atomic-free: rank from deg pass) ----------------
__global__ __launch_bounds__(256) void k_scatter(
    const int* __restrict__ ei, const float* __restrict__ ea,
    const int* __restrict__ off, const int* __restrict__ rank,
    int4* __restrict__ erec)
{
    int e = blockIdx.x * 256 + threadIdx.x;
    int src = ei[e];
    int dst = ei[N_EDGES + e];
    float a0 = ea[e * 3 + 0];
    float a1 = ea[e * 3 + 1];
    float a2 = ea[e * 3 + 2];
    int pos = off[dst] + rank[e];
    erec[pos] = make_int4(src, __float_as_int(a0), __float_as_int(a1), __float_as_int(a2));
}

// ---------------- fused node pipeline (MFMA): MLP(2x LN) -> xl8/xr/hres, + deg/rank fold ----------------
// blocks [0,1024): 4 waves x 16 nodes; blocks [1024,5120): degree count + edge rank.
// R15 body (direct stores; R16's transposed variant was neutral and cost absmax margin).
__global__ __launch_bounds__(256, 4) void k_fused(
    const float* __restrict__ in,
    const u16* __restrict__ wt0, const u16* __restrict__ wt1, const u16* __restrict__ wt,
    const float* __restrict__ b0, const float* __restrict__ g0, const float* __restrict__ be0,
    const float* __restrict__ b1, const float* __restrict__ g1, const float* __restrict__ be1,
    const float* __restrict__ bl, const float* __restrict__ br, const float* __restrict__ gbias,
    const int* __restrict__ ei, int* __restrict__ deg, int* __restrict__ rank,
    u8* __restrict__ xl8, u16* __restrict__ xr, u16* __restrict__ hres)
{
    if (blockIdx.x >= 1024) {
        int e = (blockIdx.x - 1024) * 256 + threadIdx.x;
        rank[e] = atomicAdd(deg + ei[N_EDGES + e], 1);   // rank = within-node slot
        return;
    }
    int wid = threadIdx.x >> 6, lane = threadIdx.x & 63;
    int l15 = lane & 15, quad = lane >> 4;
    int m0 = (blockIdx.x * 4 + wid) * 16;

    __shared__ u16 xbuf[4][16][136];   // per-wave x-strip (bf16)

    f32x4 acc[8];

    // ===== layer 0: [16 x 96] @ W0 -> [16 x 128], relu + LN =====
#pragma unroll
    for (int t = 0; t < 8; t++) acc[t] = {0.f, 0.f, 0.f, 0.f};
#pragma unroll
    for (int kk = 0; kk < 3; kk++) {
        const float* ap = in + (long)(m0 + l15) * IN_DIM + kk * 32 + quad * 8;
        float4 fa = *(const float4*)(ap);
        float4 fb = *(const float4*)(ap + 4);
        bf16x8 af;
        af[0] = (short)f2bf(fa.x); af[1] = (short)f2bf(fa.y);
        af[2] = (short)f2bf(fa.z); af[3] = (short)f2bf(fa.w);
        af[4] = (short)f2bf(fb.x); af[5] = (short)f2bf(fb.y);
        af[6] = (short)f2bf(fb.z); af[7] = (short)f2bf(fb.w);
#pragma unroll
        for (int t = 0; t < 8; t++) {
            bf16x8 bf = *(const bf16x8*)(wt0 + (t * 16 + l15) * IN_DIM + kk * 32 + quad * 8);
            acc[t] = __builtin_amdgcn_mfma_f32_16x16x32_bf16(af, bf, acc[t], 0, 0, 0);
        }
    }
    {
        float bv[8], gv[8], bev[8];
#pragma unroll
        for (int t = 0; t < 8; t++) {
            int col = t * 16 + l15;
            bv[t] = b0[col]; gv[t] = g0[col]; bev[t] = be0[col];
        }
#pragma unroll
        for (int g = 0; g < 4; g++) {
            float s_ = 0.f, q_ = 0.f;
#pragma unroll
            for (int t = 0; t < 8; t++) {
                float x = fmaxf(acc[t][g] + bv[t], 0.f);
                acc[t][g] = x;
                s_ += x;
                q_ = fmaf(x, x, q_);
            }
            s_ = red16(s_);
            q_ = red16(q_);
            float mu = s_ * (1.f / HID);
            float var = q_ * (1.f / HID) - mu * mu;
            float rs = rsqrtf(fmaxf(var, 0.f) + 1e-5f);
#pragma unroll
            for (int t = 0; t < 8; t++) {
                float y = (acc[t][g] - mu) * rs * gv[t] + bev[t];
                xbuf[wid][quad * 4 + g][t * 16 + l15] = f2bf(y);
            }
        }
    }

    // ===== layer 1: [16 x 128] @ W1 -> [16 x 128], relu + LN =====
#pragma unroll
    for (int t = 0; t < 8; t++) acc[t] = {0.f, 0.f, 0.f, 0.f};
#pragma unroll
    for (int kk = 0; kk < 4; kk++) {
        bf16x8 af = *(const bf16x8*)(&xbuf[wid][l15][kk * 32 + quad * 8]);
#pragma unroll
        for (int t = 0; t < 8; t++) {
            bf16x8 bf = *(const bf16x8*)(wt1 + (t * 16 + l15) * HID + kk * 32 + quad * 8);
            acc[t] = __builtin_amdgcn_mfma_f32_16x16x32_bf16(af, bf, acc[t], 0, 0, 0);
        }
    }
    {
        float bv[8], gv[8], bev[8];
#pragma unroll
        for (int t = 0; t < 8; t++) {
            int col = t * 16 + l15;
            bv[t] = b1[col]; gv[t] = g1[col]; bev[t] = be1[col];
        }
#pragma unroll
        for (int g = 0; g < 4; g++) {
            float s_ = 0.f, q_ = 0.f;
#pragma unroll
            for (int t = 0; t < 8; t++) {
                float x = fmaxf(acc[t][g] + bv[t], 0.f);
                acc[t][g] = x;
                s_ += x;
                q_ = fmaf(x, x, q_);
            }
            s_ = red16(s_);
            q_ = red16(q_);
            float mu = s_ * (1.f / HID);
            float var = q_ * (1.f / HID) - mu * mu;
            float rs = rsqrtf(fmaxf(var, 0.f) + 1e-5f);
#pragma unroll
            for (int t = 0; t < 8; t++) {
                float y = (acc[t][g] - mu) * rs * gv[t] + bev[t];
                xbuf[wid][quad * 4 + g][t * 16 + l15] = f2bf(y);
            }
        }
    }

    // ===== projections: x1 @ {Wl|Wr|Wres} + bias -> xl8(fp8)/xr/hres =====
    for (int nT = 0; nT < 3; nT++) {
        f32x4 pacc[16];
#pragma unroll
        for (int t = 0; t < 16; t++) pacc[t] = {0.f, 0.f, 0.f, 0.f};
#pragma unroll
        for (int kk = 0; kk < 4; kk++) {
            bf16x8 af = *(const bf16x8*)(&xbuf[wid][l15][kk * 32 + quad * 8]);
#pragma unroll
            for (int t = 0; t < 16; t++) {
                bf16x8 bf = *(const bf16x8*)(wt + (long)(nT * 256 + t * 16 + l15) * HID + kk * 32 + quad * 8);
                pacc[t] = __builtin_amdgcn_mfma_f32_16x16x32_bf16(af, bf, pacc[t], 0, 0, 0);
            }
        }
        if (nT == 0) {
#pragma unroll
            for (int t = 0; t < 16; t++) {
                int col = t * 16 + l15;
                float bvv = bl[col];
#pragma unroll
                for (int g = 0; g < 4; g++) {
                    xl8[(long)(m0 + quad * 4 + g) * OUTD + col] = ftofp8(pacc[t][g] + bvv);
                }
            }
        } else {
            const float* bias = (nT == 1) ? br : gbias;
            u16* dst = (nT == 1) ? xr : hres;
#pragma unroll
            for (int t = 0; t < 16; t++) {
                int col = t * 16 + l15;
                float bvv = bias[col];
#pragma unroll
                for (int g = 0; g < 4; g++) {
                    dst[(long)(m0 + quad * 4 + g) * OUTD + col] = f2bf(pacc[t][g] + bvv);
                }
            }
        }
    }
}

// ---------------- fused aggregation (R15, measured 312 µs): plain-exp softmax, ----------------
// 2 edges/iter, pipelined, DPP wave-sum, fp8 xl gather (256B rows).
__global__ __launch_bounds__(256, 6) void k_agg_fused(
    const int* __restrict__ off, const int4* __restrict__ erec,
    const u8* __restrict__ xl8, const u16* __restrict__ xr, const u16* __restrict__ hres,
    const float* __restrict__ We, const float* __restrict__ att,
    const float* __restrict__ g2, const float* __restrict__ be2,
    const float* __restrict__ wqT, const float* __restrict__ bq,
    float* __restrict__ out)
{
    int wid = threadIdx.x >> 6, lane = threadIdx.x & 63;
    int n = blockIdx.x * 4 + wid;
    int j0 = lane * 4;
    __shared__ float lds[4][OUTD + 4];

    float4 w0 = *(const float4*)(We + j0);
    float4 w1 = *(const float4*)(We + OUTD + j0);
    float4 w2 = *(const float4*)(We + 2 * OUTD + j0);
    float4 av = *(const float4*)(att + j0);

    ushort4 xrv = *(const ushort4*)(xr + (long)n * OUTD + j0);
    float xr0 = bf2f(xrv.x), xr1 = bf2f(xrv.y), xr2 = bf2f(xrv.z), xr3 = bf2f(xrv.w);

    int beg = off[n], end = off[n + 1];

    float s = 0.f;
    float a0 = 0.f, a1 = 0.f, a2 = 0.f, a3 = 0.f;

    if (beg < end) {
        int4 r0 = erec[beg];
        int4 r1 = erec[(beg + 1 < end) ? beg + 1 : beg];
        u32 v0 = *(const u32*)(xl8 + (long)r0.x * OUTD + j0);
        u32 v1 = *(const u32*)(xl8 + (long)r1.x * OUTD + j0);

        for (int i = beg; i < end; i += 2) {
            int ip2 = (i + 2 < end) ? i + 2 : end - 1;
            int ip3 = (i + 3 < end) ? i + 3 : end - 1;
            int4 nr0 = erec[ip2];
            int4 nr1 = erec[ip3];
            u32 nv0 = *(const u32*)(xl8 + (long)nr0.x * OUTD + j0);
            u32 nv1 = *(const u32*)(xl8 + (long)nr1.x * OUTD + j0);

            float x00 = f8dec(v0 & 255u), x01 = f8dec((v0 >> 8) & 255u);
            float x02 = f8dec((v0 >> 16) & 255u), x03 = f8dec(v0 >> 24);
            float x10 = f8dec(v1 & 255u), x11 = f8dec((v1 >> 8) & 255u);
            float x12 = f8dec((v1 >> 16) & 255u), x13 = f8dec(v1 >> 24);

            float p0, p1;
            {
                float ea0 = __int_as_float(r0.y), ea1 = __int_as_float(r0.z), ea2 = __int_as_float(r0.w);
                float t0 = x00 + xr0 + ea0 * w0.x + ea1 * w1.x + ea2 * w2.x;
                float t1 = x01 + xr1 + ea0 * w0.y + ea1 * w1.y + ea2 * w2.y;
                float t2 = x02 + xr2 + ea0 * w0.z + ea1 * w1.z + ea2 * w2.z;
                float t3 = x03 + xr3 + ea0 * w0.w + ea1 * w1.w + ea2 * w2.w;
                p0 = fmaxf(t0, 0.2f * t0) * av.x;
                p0 = fmaf(fmaxf(t1, 0.2f * t1), av.y, p0);
                p0 = fmaf(fmaxf(t2, 0.2f * t2), av.z, p0);
                p0 = fmaf(fmaxf(t3, 0.2f * t3), av.w, p0);
            }
            {
                float ea0 = __int_as_float(r1.y), ea1 = __int_as_float(r1.z), ea2 = __int_as_float(r1.w);
                float t0 = x10 + xr0 + ea0 * w0.x + ea1 * w1.x + ea2 * w2.x;
                float t1 = x11 + xr1 + ea0 * w0.y + ea1 * w1.y + ea2 * w2.y;
                float t2 = x12 + xr2 + ea0 * w0.z + ea1 * w1.z + ea2 * w2.z;
                float t3 = x13 + xr3 + ea0 * w0.w + ea1 * w1.w + ea2 * w2.w;
                p1 = fmaxf(t0, 0.2f * t0) * av.x;
                p1 = fmaf(fmaxf(t1, 0.2f * t1), av.y, p1);
                p1 = fmaf(fmaxf(t2, 0.2f * t2), av.z, p1);
                p1 = fmaf(fmaxf(t3, 0.2f * t3), av.w, p1);
            }

            p0 = wave_sum_bcast(p0);
            p1 = wave_sum_bcast(p1);
            if (i + 1 >= end) p1 = -1.0e30f;   // exp -> 0

            float e0 = __expf(p0);
            float e1 = __expf(p1);
            s += e0 + e1;
            a0 = fmaf(e0, x00, fmaf(e1, x10, a0));
            a1 = fmaf(e0, x01, fmaf(e1, x11, a1));
            a2 = fmaf(e0, x02, fmaf(e1, x12, a2));
            a3 = fmaf(e0, x03, fmaf(e1, x13, a3));

            r0 = nr0; r1 = nr1; v0 = nv0; v1 = nv1;
        }
    }

    float inv = (end > beg) ? 1.f / s : 0.f;

    ushort4 hv = *(const ushort4*)(hres + (long)n * OUTD + j0);
    float h0 = fmaxf(fmaf(a0, inv, bf2f(hv.x)), 0.f);
    float h1 = fmaxf(fmaf(a1, inv, bf2f(hv.y)), 0.f);
    float h2 = fmaxf(fmaf(a2, inv, bf2f(hv.z)), 0.f);
    float h3 = fmaxf(fmaf(a3, inv, bf2f(hv.w)), 0.f);

    float sum = h0 + h1 + h2 + h3;
    float sq = h0 * h0 + h1 * h1 + h2 * h2 + h3 * h3;
    sum = wave_sum_bcast(sum);
    sq = wave_sum_bcast(sq);
    float mu = sum * (1.f / OUTD);
    float var = sq * (1.f / OUTD) - mu * mu;
    float rs = rsqrtf(fmaxf(var, 0.f) + 1e-5f);

    float4 gv = *(const float4*)(g2 + j0);
    float4 bv = *(const float4*)(be2 + j0);
    float4 y;
    y.x = (h0 - mu) * rs * gv.x + bv.x;
    y.y = (h1 - mu) * rs * gv.y + bv.y;
    y.z = (h2 - mu) * rs * gv.z + bv.z;
    y.w = (h3 - mu) * rs * gv.w + bv.w;
    *(float4*)(&lds[wid][j0]) = y;
    __syncthreads();

    if (lane < N_ACT) {
        const float* wq = wqT + lane * OUTD;
        float qv = bq[lane];
#pragma unroll 4
        for (int j = 0; j < OUTD; j += 4) {
            float4 lv = *(const float4*)(&lds[wid][j]);
            float4 wv = *(const float4*)(wq + j);
            qv = fmaf(lv.x, wv.x, qv);
            qv = fmaf(lv.y, wv.y, qv);
            qv = fmaf(lv.z, wv.z, qv);
            qv = fmaf(lv.w, wv.w, qv);
        }
        out[(long)n * N_ACT + lane] = qv;
    }
}

extern "C" void kernel_launch(void* const* d_in, const int* in_sizes, int n_in,
                              void* d_out, int out_size, void* d_ws, size_t ws_size,
                              hipStream_t stream) {
    (void)in_sizes; (void)n_in; (void)out_size; (void)ws_size;
    const float* inp  = (const float*)d_in[0];
    const int*   ei   = (const int*)d_in[1];
    const float* ea   = (const float*)d_in[2];
    const float* W0   = (const float*)d_in[3];
    const float* b0   = (const float*)d_in[4];
    const float* g0   = (const float*)d_in[5];
    const float* be0  = (const float*)d_in[6];
    const float* W1   = (const float*)d_in[7];
    const float* b1   = (const float*)d_in[8];
    const float* g1   = (const float*)d_in[9];
    const float* be1  = (const float*)d_in[10];
    const float* Wl   = (const float*)d_in[11];
    const float* bl   = (const float*)d_in[12];
    const float* Wr   = (const float*)d_in[13];
    const float* br   = (const float*)d_in[14];
    const float* We   = (const float*)d_in[15];
    const float* att  = (const float*)d_in[16];
    const float* Wres = (const float*)d_in[17];
    const float* gbias= (const float*)d_in[18];
    const float* g2   = (const float*)d_in[19];
    const float* be2  = (const float*)d_in[20];
    const float* Wq   = (const float*)d_in[21];
    const float* bq   = (const float*)d_in[22];
    float* out = (float*)d_out;

    char* ws = (char*)d_ws;
    size_t o = 0;
    auto alloc = [&](size_t bytes) -> void* {
        void* p = ws + o;
        o += (bytes + 255) & ~(size_t)255;
        return p;
    };
    u8*    xl8    = (u8*)   alloc((size_t)N_NODES * OUTD);        // 16 MiB (fp8 e4m3)
    u16*   xr     = (u16*)  alloc((size_t)N_NODES * OUTD * 2);    // 32 MiB
    u16*   hres   = (u16*)  alloc((size_t)N_NODES * OUTD * 2);    // 32 MiB
    int*   deg    = (int*)  alloc((size_t)N_NODES * 4);           // 256 KiB
    int*   off    = (int*)  alloc((size_t)(N_NODES + 1) * 4);
    int*   rank   = (int*)  alloc((size_t)N_EDGES * 4);           // 4 MiB (edge slot from deg pass)
    int4*  erec   = (int4*) alloc((size_t)N_EDGES * 16);          // 16 MiB
    u16*   wt     = (u16*)  alloc((size_t)768 * HID * 2);         // 192 KiB  gat [768][128]
    u16*   wt0    = (u16*)  alloc((size_t)HID * IN_DIM * 2);      // 24 KiB   W0^T [128][96]
    u16*   wt1    = (u16*)  alloc((size_t)HID * HID * 2);         // 32 KiB   W1^T [128][128]
    float* wqT    = (float*)alloc((size_t)N_ACT * OUTD * 4);      // 20 KiB

    k_prep<<<772, 256, 0, stream>>>(deg, Wl, Wr, Wres, wt, W0, wt0, W1, wt1, Wq, wqT);
    k_fused<<<1024 + N_EDGES / 256, 256, 0, stream>>>(inp, wt0, wt1, wt,
        b0, g0, be0, b1, g1, be1, bl, br, gbias, ei, deg, rank, xl8, xr, hres);
    k_scan<<<1, 1024, 0, stream>>>(deg, off);
    k_scatter<<<N_EDGES / 256, 256, 0, stream>>>(ei, ea, off, rank, erec);
    k_agg_fused<<<N_NODES / 4, 256, 0, stream>>>(off, erec, xl8, xr, hres, We, att, g2, be2, wqT, bq, out);
}